// Round 18
// baseline (107.715 us; speedup 1.0000x reference)
//
#include <hip/hip_runtime.h>

// Batched ADMM QP solver. One block (256 thr, 4 waves) per batch. Monolith.
// Round-18: AtA re-tiled 4x4/thread (2 b128/k instead of 5 DS/k -- setup is
//   DS-issue-bound per r17 null) with K handed to GJ layout via a transient
//   kls LDS buffer aliased over the post-GJ scratch arrays (manual smem plan,
//   39.2 KB -> 4 blocks/CU). K bitwise identical to r17; GJ (blocked-4) and
//   everything downstream unchanged.
// Setup: K = Q + sigma*I + At*diag(rho)*A (rho_eq=100); blocked-4 register GJ;
//   c = Kinv*p; d = -A*c; P = A*Kinv*At per-lane frags, vf2 pk for v_pk_fma_f32.
// Iterate <=800x (unrolled x2): over-relaxed ADMM alpha=1.8 scaled-dual form,
//   warm start z0 = med3(d,l,u); lazy zero-critical-path exit (EPS 5e-4).
// Epilogue: x = Kinv*(At*wt) - c.

#define ITERS 800
#define SIGMA 1e-6f
#define WAM  68     // amat row stride
#define MROW 96     // M half-buffer row stride
#define WROW 12     // padded w chunk stride (10 used + 2 pad)
#define KLW  68     // kls row stride
#define EPS  5e-4f
#define ALPHA 1.8f
#define BETA  (-0.8f)   // 1 - ALPHA
#define RHO_E 100.0f    // penalty on equality rows (rows 0..15)

typedef float vf2 __attribute__((ext_vector_type(2)));
typedef float vf4 __attribute__((ext_vector_type(4)));

__device__ __forceinline__ float dpp_add(float x, const int ctrl) {
    int yi;
    switch (ctrl) {
        case 0xB1:  yi = __builtin_amdgcn_update_dpp(0, __float_as_int(x), 0xB1,  0xF, 0xF, true); break;
        case 0x4E:  yi = __builtin_amdgcn_update_dpp(0, __float_as_int(x), 0x4E,  0xF, 0xF, true); break;
        default:    yi = __builtin_amdgcn_update_dpp(0, __float_as_int(x), 0x141, 0xF, 0xF, true); break;
    }
    return x + __int_as_float(yi);
}

__global__ __launch_bounds__(256, 4)
void admm_qp_kernel(const float* __restrict__ Q, const float* __restrict__ p_,
                    const float* __restrict__ A, const float* __restrict__ bvec,
                    const float* __restrict__ G, const float* __restrict__ h,
                    float* __restrict__ out)
{
    // Manual smem plan (floats): amat[0..5440) | U=5440: kls[4352] transient,
    // aliased by { fcolB4:U+0(256) prowT:U+256(544) mh:U+800(3072)
    // fcol:U+3872(64) pvec:U+3936(64) cvec:U+4000(64) dvec:U+4064(80)
    // wbuf:U+4144(192) flagsL:U+4336(4) } -- all GJ-or-later.
    __shared__ __align__(16) float smem[9792];
    float* const amat   = smem;
    float* const U      = smem + 5440;
    float* const kls    = U;
    float4* const fcolB4 = (float4*)U;
    float* const prowT  = U + 256;
    float* const mh     = U + 800;
    float* const fcol   = U + 3872;
    float* const pvec   = U + 3936;
    float* const cvec   = U + 4000;
    float* const dvec   = U + 4064;
    float* const wbuf   = U + 4144;
    unsigned int* const flagsL = (unsigned int*)(U + 4336);

    const int b  = blockIdx.x;
    const int t  = threadIdx.x;
    const int i  = t >> 2, qc = t & 3;   // GJ/epilogue mapping
    const int g  = t >> 3, cc = t & 7;   // iteration mapping
    const int tu = t >> 4, tv = t & 15;  // AtA 4x4-tile mapping

    const float* Ab = A + (size_t)b * 16 * 64;
    const float* Gb = G + (size_t)b * 64 * 64;
    const float* Qb = Q + (size_t)b * 64 * 64;

    // ---- stage Amat=[A;G] ----
    for (int e = t; e < 80 * 16; e += 256) {
        int row = e >> 4, seg = e & 15;
        const float* src = (row < 16) ? (Ab + row * 64 + seg * 4)
                                      : (Gb + (row - 16) * 64 + seg * 4);
        *(float4*)&amat[row * WAM + seg * 4] = *(const float4*)src;
    }
    __syncthreads();

    // ---- K = At*diag(rho)*A + Q + sigma*I, 4x4 tile (rows tu*4.., cols tv*4..) ----
    float ka00=0.f,ka01=0.f,ka02=0.f,ka03=0.f, ka10=0.f,ka11=0.f,ka12=0.f,ka13=0.f;
    float ka20=0.f,ka21=0.f,ka22=0.f,ka23=0.f, ka30=0.f,ka31=0.f,ka32=0.f,ka33=0.f;
    for (int k = 0; k < 16; ++k) {          // equality rows: weight RHO_E
        float4 ra = *(const float4*)&amat[k * WAM + tu * 4];
        float4 rb = *(const float4*)&amat[k * WAM + tv * 4];
        float a0 = ra.x * RHO_E, a1 = ra.y * RHO_E, a2 = ra.z * RHO_E, a3 = ra.w * RHO_E;
        ka00 += a0*rb.x; ka01 += a0*rb.y; ka02 += a0*rb.z; ka03 += a0*rb.w;
        ka10 += a1*rb.x; ka11 += a1*rb.y; ka12 += a1*rb.z; ka13 += a1*rb.w;
        ka20 += a2*rb.x; ka21 += a2*rb.y; ka22 += a2*rb.z; ka23 += a2*rb.w;
        ka30 += a3*rb.x; ka31 += a3*rb.y; ka32 += a3*rb.z; ka33 += a3*rb.w;
    }
    for (int k = 16; k < 80; ++k) {         // inequality rows: weight 1
        float4 ra = *(const float4*)&amat[k * WAM + tu * 4];
        float4 rb = *(const float4*)&amat[k * WAM + tv * 4];
        ka00 += ra.x*rb.x; ka01 += ra.x*rb.y; ka02 += ra.x*rb.z; ka03 += ra.x*rb.w;
        ka10 += ra.y*rb.x; ka11 += ra.y*rb.y; ka12 += ra.y*rb.z; ka13 += ra.y*rb.w;
        ka20 += ra.z*rb.x; ka21 += ra.z*rb.y; ka22 += ra.z*rb.z; ka23 += ra.z*rb.w;
        ka30 += ra.w*rb.x; ka31 += ra.w*rb.y; ka32 += ra.w*rb.z; ka33 += ra.w*rb.w;
    }
    {   // + Q + sigma*I, store tiles to kls
        float4 q0 = *(const float4*)&Qb[(tu*4+0)*64 + tv*4];
        float4 q1 = *(const float4*)&Qb[(tu*4+1)*64 + tv*4];
        float4 q2 = *(const float4*)&Qb[(tu*4+2)*64 + tv*4];
        float4 q3 = *(const float4*)&Qb[(tu*4+3)*64 + tv*4];
        ka00+=q0.x; ka01+=q0.y; ka02+=q0.z; ka03+=q0.w;
        ka10+=q1.x; ka11+=q1.y; ka12+=q1.z; ka13+=q1.w;
        ka20+=q2.x; ka21+=q2.y; ka22+=q2.z; ka23+=q2.w;
        ka30+=q3.x; ka31+=q3.y; ka32+=q3.z; ka33+=q3.w;
        if (tu == tv) { ka00 += SIGMA; ka11 += SIGMA; ka22 += SIGMA; ka33 += SIGMA; }
        *(float4*)&kls[(tu*4+0)*KLW + tv*4] = make_float4(ka00,ka01,ka02,ka03);
        *(float4*)&kls[(tu*4+1)*KLW + tv*4] = make_float4(ka10,ka11,ka12,ka13);
        *(float4*)&kls[(tu*4+2)*KLW + tv*4] = make_float4(ka20,ka21,ka22,ka23);
        *(float4*)&kls[(tu*4+3)*KLW + tv*4] = make_float4(ka30,ka31,ka32,ka33);
    }
    __syncthreads();

    // ---- hand off to GJ register layout: ar = K[i][qc*16..+15] ----
    float ar[16];
#pragma unroll
    for (int c4_ = 0; c4_ < 4; ++c4_) {
        float4 v = *(const float4*)&kls[i * KLW + qc * 16 + 4 * c4_];
        ar[4*c4_+0] = v.x; ar[4*c4_+1] = v.y; ar[4*c4_+2] = v.z; ar[4*c4_+3] = v.w;
    }
    __syncthreads();   // kls dead; fcolB4/prowT may now alias it

    // ---- BLOCKED-4 register Gauss-Jordan (unchanged from r17) ----
#pragma unroll
    for (int r = 0; r < 16; ++r) {
        const int pv0 = 4 * r;
        const int qp  = r >> 2;
        const int lc  = (4 * r) & 15;
        if (qc == qp) fcolB4[i] = make_float4(ar[lc], ar[lc+1], ar[lc+2], ar[lc+3]);
        if ((i >> 2) == r) {
            const int m = i & 3;
#pragma unroll
            for (int c = 0; c < 16; ++c) prowT[qc * 136 + c * 8 + m] = ar[c];
        }
        __syncthreads();
        float4 fb = fcolB4[i];
        float4 r0 = fcolB4[pv0+0], r1 = fcolB4[pv0+1];
        float4 r2 = fcolB4[pv0+2], r3 = fcolB4[pv0+3];
        float ed = 1.0f / (r0.x * r1.y - r0.y * r1.x);
        float ei00 =  r1.y * ed, ei01 = -r0.y * ed, ei10 = -r1.x * ed, ei11 = r0.x * ed;
        float ge00 = r2.x*ei00 + r2.y*ei10, ge01 = r2.x*ei01 + r2.y*ei11;
        float ge10 = r3.x*ei00 + r3.y*ei10, ge11 = r3.x*ei01 + r3.y*ei11;
        float s00 = r2.z - (ge00*r0.z + ge01*r1.z), s01 = r2.w - (ge00*r0.w + ge01*r1.w);
        float s10 = r3.z - (ge10*r0.z + ge11*r1.z), s11 = r3.w - (ge10*r0.w + ge11*r1.w);
        float sd = 1.0f / (s00 * s11 - s01 * s10);
        float si00 =  s11 * sd, si01 = -s01 * sd, si10 = -s10 * sd, si11 = s00 * sd;
        float ef00 = ei00*r0.z + ei01*r1.z, ef01 = ei00*r0.w + ei01*r1.w;
        float ef10 = ei10*r0.z + ei11*r1.z, ef11 = ei10*r0.w + ei11*r1.w;
        float es00 = ef00*si00 + ef01*si10, es01 = ef00*si01 + ef01*si11;
        float es10 = ef10*si00 + ef11*si10, es11 = ef10*si01 + ef11*si11;
        float b00_ = ei00 + es00*ge00 + es01*ge10, b01_ = ei01 + es00*ge01 + es01*ge11;
        float b10_ = ei10 + es10*ge00 + es11*ge10, b11_ = ei11 + es10*ge01 + es11*ge11;
        float b02_ = -es00, b03_ = -es01, b12_ = -es10, b13_ = -es11;
        float b20_ = -(si00*ge00 + si01*ge10), b21_ = -(si00*ge01 + si01*ge11);
        float b30_ = -(si10*ge00 + si11*ge10), b31_ = -(si10*ge01 + si11*ge11);
        float b22_ = si00, b23_ = si01, b32_ = si10, b33_ = si11;
        float g0 = fb.x*b00_ + fb.y*b10_ + fb.z*b20_ + fb.w*b30_;
        float g1 = fb.x*b01_ + fb.y*b11_ + fb.z*b21_ + fb.w*b31_;
        float g2 = fb.x*b02_ + fb.y*b12_ + fb.z*b22_ + fb.w*b32_;
        float g3 = fb.x*b03_ + fb.y*b13_ + fb.z*b23_ + fb.w*b33_;
        const bool isPiv = ((i >> 2) == r);
        const int  m     = i & 3;
        float c0_, c1_, c2_, c3_;
        if (isPiv) {
            c0_ = (m==0)?b00_:(m==1)?b10_:(m==2)?b20_:b30_;
            c1_ = (m==0)?b01_:(m==1)?b11_:(m==2)?b21_:b31_;
            c2_ = (m==0)?b02_:(m==1)?b12_:(m==2)?b22_:b32_;
            c3_ = (m==0)?b03_:(m==1)?b13_:(m==2)?b23_:b33_;
        } else { c0_ = g0; c1_ = g1; c2_ = g2; c3_ = g3; }
#pragma unroll
        for (int c = 0; c < 16; ++c) {
            float4 pr = *(const float4*)&prowT[qc * 136 + c * 8];
            float s = c0_*pr.x + c1_*pr.y + c2_*pr.z + c3_*pr.w;
            ar[c] = isPiv ? s : (ar[c] - s);
        }
        if (qc == qp) {
            ar[lc+0] = isPiv ? c0_ : -c0_;
            ar[lc+1] = isPiv ? c1_ : -c1_;
            ar[lc+2] = isPiv ? c2_ : -c2_;
            ar[lc+3] = isPiv ? c3_ : -c3_;
        }
        __syncthreads();
    }

    // ---- post-GJ loads (pvec was deferred: its slot aliased kls) ----
    if (t < 64) pvec[t] = p_[(size_t)b * 64 + t];
    if (t < 2 * 8 * WROW) wbuf[t] = 0.f;
    if (t < 4) flagsL[t] = 0u;
    __syncthreads();

    // ---- c = Kinv*p ----
    float creg;
    {
        float cacc = 0.f;
#pragma unroll
        for (int c4_ = 0; c4_ < 4; ++c4_) {
            float4 pv4 = *(const float4*)&pvec[qc * 16 + 4 * c4_];
            cacc += ar[4*c4_]*pv4.x + ar[4*c4_+1]*pv4.y + ar[4*c4_+2]*pv4.z + ar[4*c4_+3]*pv4.w;
        }
        cacc = dpp_add(cacc, 0xB1);
        cacc = dpp_add(cacc, 0x4E);
        creg = cacc;
        if (qc == 0) cvec[i] = cacc;
    }
    __syncthreads();

    // ---- d = -A*c ----
    if (t < 80) {
        float acc = 0.f;
#pragma unroll
        for (int k4 = 0; k4 < 16; ++k4) {
            float4 avv = *(const float4*)&amat[t * WAM + 4 * k4];
            float4 cv4 = *(const float4*)&cvec[4 * k4];
            acc += avv.x*cv4.x + avv.y*cv4.y + avv.z*cv4.z + avv.w*cv4.w;
        }
        dvec[t] = -acc;
    }
    __syncthreads();

    // ---- per-lane row state + warm start z0 = med3(d, l, u) ----
    int rr[3];
    float dR[3], lR[3], uR[3], yR[3], zmR[3], rR[3], w0R[3];
#pragma unroll
    for (int j = 0; j < 3; ++j) {
        int r = 3 * g + j; if (r > 79) r = 79;
        rr[j] = r;
        dR[j] = dvec[r];
        if (r < 16) { float bb = bvec[(size_t)b * 16 + r]; lR[j] = bb; uR[j] = bb; rR[j] = RHO_E; }
        else        { lR[j] = -1e8f; uR[j] = h[(size_t)b * 64 + (r - 16)]; rR[j] = 1.0f; }
        float z0 = __builtin_amdgcn_fmed3f(dR[j], lR[j], uR[j]);
        yR[j] = 0.f; zmR[j] = BETA * z0; w0R[j] = rR[j] * z0;
    }

    // ---- P = A*(Kinv*At): two k-passes ----
    float pacc[3][10];
#pragma unroll
    for (int j = 0; j < 3; ++j)
#pragma unroll
        for (int c = 0; c < 10; ++c) pacc[j][c] = 0.f;

    for (int ps = 0; ps < 2; ++ps) {
        if ((t >> 7) == ps) {
            const int mrow = i & 31;
            for (int jo = 0; jo < 8; ++jo) {
#pragma unroll
                for (int ji = 0; ji < 10; ++ji) {
                    const int j = jo * 10 + ji;
                    const float* rj = &amat[j * WAM + qc * 16];
                    float acc = 0.f;
#pragma unroll
                    for (int c4_ = 0; c4_ < 4; ++c4_) {
                        float4 av = *(const float4*)&rj[4 * c4_];
                        acc += ar[4*c4_]*av.x + ar[4*c4_+1]*av.y + ar[4*c4_+2]*av.z + ar[4*c4_+3]*av.w;
                    }
                    acc = dpp_add(acc, 0xB1);
                    acc = dpp_add(acc, 0x4E);
                    if (qc == (ji & 3)) mh[mrow * MROW + jo * WROW + ji] = acc;
                }
            }
        }
        __syncthreads();
#pragma unroll 2
        for (int kb = 0; kb < 8; ++kb) {
            float a0[4], a1[4], a2[4];
            { float4 v = *(const float4*)&amat[rr[0]*WAM + ps*32 + kb*4]; a0[0]=v.x;a0[1]=v.y;a0[2]=v.z;a0[3]=v.w; }
            { float4 v = *(const float4*)&amat[rr[1]*WAM + ps*32 + kb*4]; a1[0]=v.x;a1[1]=v.y;a1[2]=v.z;a1[3]=v.w; }
            { float4 v = *(const float4*)&amat[rr[2]*WAM + ps*32 + kb*4]; a2[0]=v.x;a2[1]=v.y;a2[2]=v.z;a2[3]=v.w; }
#pragma unroll
            for (int kk = 0; kk < 4; ++kk) {
                const float* mrp = &mh[(kb * 4 + kk) * MROW + cc * WROW];
                float4 ma = *(const float4*)&mrp[0];
                float4 mb = *(const float4*)&mrp[4];
                float2 mc = *(const float2*)&mrp[8];
                float m[10] = {ma.x, ma.y, ma.z, ma.w, mb.x, mb.y, mb.z, mb.w, mc.x, mc.y};
#pragma unroll
                for (int c = 0; c < 10; ++c) {
                    pacc[0][c] += a0[kk] * m[c];
                    pacc[1][c] += a1[kk] * m[c];
                    pacc[2][c] += a2[kk] * m[c];
                }
            }
        }
        __syncthreads();
    }

    // ---- pack P fragments into vf2 pairs ----
    vf2 pk0[5], pk1[5], pk2[5];
#pragma unroll
    for (int c5 = 0; c5 < 5; ++c5) {
        pk0[c5] = (vf2){pacc[0][2*c5], pacc[0][2*c5+1]};
        pk1[c5] = (vf2){pacc[1][2*c5], pacc[1][2*c5+1]};
        pk2[c5] = (vf2){pacc[2][2*c5], pacc[2][2*c5+1]};
    }

    // ---- iterations (over-relaxed, diag-rho, warm-started), unrolled x2 ----
    const int wrow  = 3 * g + cc;
    const bool wvalid = (cc < 3) && (wrow < 80);
    const int widx  = (wrow < 80) ? ((wrow / 10) * WROW + (wrow % 10)) : 0;
    const float rsel   = (cc == 1) ? rR[1] : ((cc == 2) ? rR[2] : rR[0]);
    const float epsSel = EPS * rsel;

    {
        float w0sel = (cc == 1) ? w0R[1] : ((cc == 2) ? w0R[2] : w0R[0]);
        if (wvalid) wbuf[widx] = w0sel;
    }
    __syncthreads();

#define RED8(a) a = dpp_add(a, 0xB1); a = dpp_add(a, 0x4E); a = dpp_add(a, 0x141);
#define UPD5(j, aj, wj) \
    { float ax = aj + dR[j]; \
      float axr = ALPHA * ax + zmR[j]; \
      float s = axr + yR[j]; \
      float z = __builtin_amdgcn_fmed3f(s, lR[j], uR[j]); \
      yR[j] = s - z; zmR[j] = BETA * z; wj = rR[j] * (z - yR[j]); }

#define ITERBODY(WCP, WNP) { \
    const float* wp = (WCP) + cc * WROW; \
    vf4 v04 = *(const vf4*)&wp[0]; \
    vf4 v47 = *(const vf4*)&wp[4]; \
    vf2 v89 = *(const vf2*)&wp[8]; \
    vf2 wv0 = __builtin_shufflevector(v04, v04, 0, 1); \
    vf2 wv1 = __builtin_shufflevector(v04, v04, 2, 3); \
    vf2 wv2 = __builtin_shufflevector(v47, v47, 0, 1); \
    vf2 wv3 = __builtin_shufflevector(v47, v47, 2, 3); \
    vf2 A0 = {0.f, 0.f}; vf2 A1 = {0.f, 0.f}; vf2 A2 = {0.f, 0.f}; \
    asm("v_pk_fma_f32 %0, %1, %2, %0" : "+v"(A0) : "v"(pk0[0]), "v"(wv0)); \
    asm("v_pk_fma_f32 %0, %1, %2, %0" : "+v"(A1) : "v"(pk1[0]), "v"(wv0)); \
    asm("v_pk_fma_f32 %0, %1, %2, %0" : "+v"(A2) : "v"(pk2[0]), "v"(wv0)); \
    asm("v_pk_fma_f32 %0, %1, %2, %0" : "+v"(A0) : "v"(pk0[1]), "v"(wv1)); \
    asm("v_pk_fma_f32 %0, %1, %2, %0" : "+v"(A1) : "v"(pk1[1]), "v"(wv1)); \
    asm("v_pk_fma_f32 %0, %1, %2, %0" : "+v"(A2) : "v"(pk2[1]), "v"(wv1)); \
    asm("v_pk_fma_f32 %0, %1, %2, %0" : "+v"(A0) : "v"(pk0[2]), "v"(wv2)); \
    asm("v_pk_fma_f32 %0, %1, %2, %0" : "+v"(A1) : "v"(pk1[2]), "v"(wv2)); \
    asm("v_pk_fma_f32 %0, %1, %2, %0" : "+v"(A2) : "v"(pk2[2]), "v"(wv2)); \
    asm("v_pk_fma_f32 %0, %1, %2, %0" : "+v"(A0) : "v"(pk0[3]), "v"(wv3)); \
    asm("v_pk_fma_f32 %0, %1, %2, %0" : "+v"(A1) : "v"(pk1[3]), "v"(wv3)); \
    asm("v_pk_fma_f32 %0, %1, %2, %0" : "+v"(A2) : "v"(pk2[3]), "v"(wv3)); \
    asm("v_pk_fma_f32 %0, %1, %2, %0" : "+v"(A0) : "v"(pk0[4]), "v"(v89)); \
    asm("v_pk_fma_f32 %0, %1, %2, %0" : "+v"(A1) : "v"(pk1[4]), "v"(v89)); \
    asm("v_pk_fma_f32 %0, %1, %2, %0" : "+v"(A2) : "v"(pk2[4]), "v"(v89)); \
    float a0 = A0.x + A0.y, a1 = A1.x + A1.y, a2 = A2.x + A2.y; \
    RED8(a0) RED8(a1) RED8(a2) \
    float w0, w1, w2; \
    UPD5(0, a0, w0) UPD5(1, a1, w1) UPD5(2, a2, w2) \
    wsel = (cc == 1) ? w1 : ((cc == 2) ? w2 : w0); \
    if (wvalid) (WNP)[widx] = wsel; }

    float* const wA = wbuf;
    float* const wB = wbuf + 8 * WROW;
    float wprev = 0.f, wsel = 0.f;
    unsigned int fvreg = 1u;
    for (int j2 = 0; j2 < ITERS / 2; ++j2) {
        ITERBODY(wA, wB)                  // it = 2*j2
        __syncthreads();
        ITERBODY(wB, wA)                  // it = 2*j2+1
        const int slot = j2 & 3;          // check every 2 iterations
        if (wvalid && fabsf(wsel - wprev) > epsSel) flagsL[slot] = 1u;
        if (t == 0) flagsL[(slot + 2) & 3] = 0u;
        wprev = wsel;
        __syncthreads();
        if (fvreg == 0u) break;           // stale-by-2-iters convergence info
        fvreg = flagsL[slot];             // non-blocking: consumed next check
    }

    // ---- epilogue: x = Kinv*(At*w_final) - c  (final w always in wA) ----
    if (t < 64) {
        float acc = 0.f;
        for (int jo = 0; jo < 8; ++jo) {
#pragma unroll
            for (int ji = 0; ji < 10; ++ji)
                acc += amat[(jo * 10 + ji) * WAM + t] * wA[jo * WROW + ji];
        }
        fcol[t] = acc;
    }
    __syncthreads();
    float xp = 0.f;
#pragma unroll
    for (int c4_ = 0; c4_ < 4; ++c4_) {
        float4 fv = *(const float4*)&fcol[qc * 16 + 4 * c4_];
        xp += ar[4*c4_]*fv.x + ar[4*c4_+1]*fv.y + ar[4*c4_+2]*fv.z + ar[4*c4_+3]*fv.w;
    }
    xp = dpp_add(xp, 0xB1);
    xp = dpp_add(xp, 0x4E);
    if (qc == 0) out[(size_t)b * 64 + i] = xp - creg;
}

extern "C" void kernel_launch(void* const* d_in, const int* in_sizes, int n_in,
                              void* d_out, int out_size, void* d_ws, size_t ws_size,
                              hipStream_t stream) {
    const float* Q    = (const float*)d_in[0];
    const float* p    = (const float*)d_in[1];
    const float* A    = (const float*)d_in[2];
    const float* bvec = (const float*)d_in[3];
    const float* G    = (const float*)d_in[4];
    const float* h    = (const float*)d_in[5];
    float* out = (float*)d_out;
    admm_qp_kernel<<<1024, 256, 0, stream>>>(Q, p, A, bvec, G, h, out);
}